// Round 9
// baseline (113.256 us; speedup 1.0000x reference)
//
#include <hip/hip_runtime.h>

#define HD __device__ __forceinline__

typedef __attribute__((ext_vector_type(4))) float f32x4;
typedef __attribute__((ext_vector_type(8))) short bf16x8;
typedef __attribute__((ext_vector_type(2))) long i64x2;

constexpr int B_ = 32, S_ = 128, DA = 256, DE = 256, K_ = 12, N_ = 128;
constexpr int W_ = S_ - K_;          // 116
constexpr int BW = B_ * W_;          // 3712

HD unsigned short f2bf(float f) {
    unsigned u = __float_as_uint(f);
    u += 0x7fffu + ((u >> 16) & 1u);          // round-to-nearest-even
    return (unsigned short)(u >> 16);
}

// ---- kernel 0: casts (A,Wp -> bf16; E -> fp8) + idxT u16 LDS-transpose ----
__global__ void k_prep(const float* __restrict__ A, const float* __restrict__ Wp,
                       const float* __restrict__ E, const int* __restrict__ idx,
                       unsigned short* __restrict__ Abf, unsigned short* __restrict__ Wpbf,
                       unsigned char* __restrict__ Ebf8, unsigned short* __restrict__ idxT) {
    int bx = blockIdx.x;
    if (bx < 1792) {                      // bf16 casts: A (1024 blocks), Wp (768)
        const float* src = (bx < 1024) ? A : Wp;
        unsigned short* dst = (bx < 1024) ? Abf : Wpbf;
        int base = (bx < 1024) ? bx : bx - 1024;
        int i = base * 256 + threadIdx.x;
        float4 v = ((const float4*)src)[i];
        ushort4 o;
        o.x = f2bf(v.x); o.y = f2bf(v.y); o.z = f2bf(v.z); o.w = f2bf(v.w);
        ((ushort4*)dst)[i] = o;
    } else if (bx < 2816) {               // E -> fp8 e4m3 (1024 blocks)
        int i = (bx - 1792) * 256 + threadIdx.x;
        float4 v = ((const float4*)E)[i];
        int w = __builtin_amdgcn_cvt_pk_fp8_f32(v.x, v.y, 0, false);
        w     = __builtin_amdgcn_cvt_pk_fp8_f32(v.z, v.w, w, true);
        ((unsigned int*)Ebf8)[i] = w;
    } else {                              // idxT: 32 blocks, one per b; both sides coalesced
        __shared__ unsigned short lt[W_][130];
        int b = bx - 2816;
        const int* ib = idx + b * N_ * W_;
        for (int i = threadIdx.x; i < N_ * W_; i += 256) {
            int n = i / W_, w = i - n * W_;
            lt[w][n] = (unsigned short)ib[i];           // coalesced read, ~2-way LDS alias
        }
        __syncthreads();
        unsigned short* ob = idxT + b * W_ * N_;
        for (int o = threadIdx.x; o < W_ * N_; o += 256) {
            int w = o >> 7, n = o & 127;
            ob[o] = lt[w][n];                           // coalesced write
        }
    }
}

// ---- kernel 1: locC8[m][k][e] = fp8(sum_a A[m][a] * Wp[k][e][a]), bf16 MFMA ----
// Transposed epilogue: mfma(Wp_frag, A_frag) -> D row = e, col = m; lane packs
// 4 consecutive-e fp8 bytes into one dword store.
__global__ __launch_bounds__(256) void k_locc(const unsigned short* __restrict__ Abf,
                                              const unsigned short* __restrict__ Wpbf,
                                              unsigned char* __restrict__ locC8) {
    int bx = blockIdx.x;
    int k  = bx / 58;
    int r  = bx % 58;
    int mt = r >> 1;
    int et = r & 1;

    __shared__ unsigned short As[128][40];
    __shared__ unsigned short Bs[128][40];

    int tid  = threadIdx.x;
    int lane = tid & 63;
    int wid  = tid >> 6;
    int wr   = wid >> 1, wc = wid & 1;   // wr: e-quadrant, wc: m-quadrant
    int l15  = lane & 15, lk = lane >> 4;

    f32x4 acc[4][4] = {};

    int srow = tid >> 1, spart = tid & 1;
    int m  = mt * 128 + srow;
    int bb = m / W_, ww = m - bb * W_;
    const unsigned short* aSrc = Abf + ((bb * S_ + ww) * DA) + spart * 16;
    const unsigned short* bSrc = Wpbf + ((k * DE + et * 128 + srow) * DA) + spart * 16;

    for (int c = 0; c < 8; ++c) {
        uint4 av0 = ((const uint4*)(aSrc + c * 32))[0];
        uint4 av1 = ((const uint4*)(aSrc + c * 32))[1];
        uint4 bv0 = ((const uint4*)(bSrc + c * 32))[0];
        uint4 bv1 = ((const uint4*)(bSrc + c * 32))[1];
        __syncthreads();
        ((uint4*)&As[srow][spart * 16])[0]     = av0;
        ((uint4*)&As[srow][spart * 16 + 8])[0] = av1;
        ((uint4*)&Bs[srow][spart * 16])[0]     = bv0;
        ((uint4*)&Bs[srow][spart * 16 + 8])[0] = bv1;
        __syncthreads();
        bf16x8 af[4], bfv[4];
        #pragma unroll
        for (int f = 0; f < 4; ++f) {
            af[f]  = *(const bf16x8*)&As[wc * 64 + f * 16 + l15][lk * 8];  // m rows
            bfv[f] = *(const bf16x8*)&Bs[wr * 64 + f * 16 + l15][lk * 8];  // e rows
        }
        #pragma unroll
        for (int fi = 0; fi < 4; ++fi)      // fi: e fragment (D row)
            #pragma unroll
            for (int fj = 0; fj < 4; ++fj)  // fj: m fragment (D col)
                acc[fi][fj] = __builtin_amdgcn_mfma_f32_16x16x32_bf16(bfv[fi], af[fj], acc[fi][fj], 0, 0, 0);
    }

    // D layout: col = lane&15 -> m, row = (lane>>4)*4 + rr -> e (4 consecutive e per lane)
    #pragma unroll
    for (int fi = 0; fi < 4; ++fi) {
        #pragma unroll
        for (int fj = 0; fj < 4; ++fj) {
            f32x4 v = acc[fi][fj];
            int mOut  = mt * 128 + wc * 64 + fj * 16 + l15;
            int eBase = et * 128 + wr * 64 + fi * 16 + lk * 4;
            int w = __builtin_amdgcn_cvt_pk_fp8_f32(v[0], v[1], 0, false);
            w     = __builtin_amdgcn_cvt_pk_fp8_f32(v[2], v[3], w, true);
            *(unsigned int*)(locC8 + (size_t)mOut * (K_ * DE) + k * DE + eBase) = w;
        }
    }
}

// ---- kernel 2: fp8 MFMA score + in-register LSE. Wave = one (b,w) pair ----
// All 36 B-gather loads hoisted into bv[9][4] (static indexing) so one latency
// burst covers everything; launch_bounds(256,2) -> 256-VGPR budget.
__global__ __launch_bounds__(256, 2) void k_score(const unsigned char* __restrict__ Ebf8,
                                                  const unsigned short* __restrict__ idxT,
                                                  const unsigned char* __restrict__ locC8,
                                                  float* __restrict__ partial) {
    int tid  = threadIdx.x;
    int lane = tid & 63;
    int wid  = tid >> 6;
    int l15  = lane & 15, lk = lane >> 4;
    int p    = blockIdx.x * 4 + wid;     // pair index < 3712
    int b    = p / W_, w = p - b * W_;

    // gather rows for all 9 col-groups (u16 table, coalesced)
    int rows[9];
    #pragma unroll
    for (int nf = 0; nf < 8; ++nf)
        rows[nf] = idxT[p * N_ + nf * 16 + l15];
    rows[8] = b * S_ + ((l15 < K_) ? (w + l15 + 1) : 0);

    // A fragments: locC8[p][k=l15][e], rows k>=12 zeroed; 4 chunks of 64 e
    i64x2 af[4];
    const unsigned char* aBase = locC8 + (size_t)p * (K_ * DE) + l15 * DE + lk * 16;
    #pragma unroll
    for (int c = 0; c < 4; ++c) {
        i64x2 a = {};
        if (l15 < K_) a = *(const i64x2*)(aBase + c * 64);
        af[c] = a;
    }

    // hoist ALL B loads (36 x 16B) before any MFMA
    i64x2 bv[9][4];
    #pragma unroll
    for (int nf = 0; nf < 9; ++nf) {
        const unsigned char* bBase = Ebf8 + (size_t)rows[nf] * DE + lk * 16;
        #pragma unroll
        for (int c = 0; c < 4; ++c)
            bv[nf][c] = *(const i64x2*)(bBase + c * 64);
    }

    f32x4 accs[9];
    #pragma unroll
    for (int nf = 0; nf < 9; ++nf) {
        f32x4 acc = {};
        #pragma unroll
        for (int c = 0; c < 4; ++c) {
            acc = __builtin_amdgcn_mfma_f32_16x16x32_fp8_fp8(af[c][0], bv[nf][c][0], acc, 0, 0, 0);
            acc = __builtin_amdgcn_mfma_f32_16x16x32_fp8_fp8(af[c][1], bv[nf][c][1], acc, 0, 0, 0);
        }
        accs[nf] = acc;
    }

    constexpr float inv_e = 1.0f / 256.0f;

    // raw-max over the 8 neg groups (this lane's col slice), then 16-lane col-reduce
    float m0[4], s0[4];
    #pragma unroll
    for (int rr = 0; rr < 4; ++rr) {
        float mx = accs[0][rr];
        #pragma unroll
        for (int nf = 1; nf < 8; ++nf) mx = fmaxf(mx, accs[nf][rr]);
        m0[rr] = mx;
    }
    #pragma unroll
    for (int off = 1; off < 16; off <<= 1)
        #pragma unroll
        for (int rr = 0; rr < 4; ++rr) m0[rr] = fmaxf(m0[rr], __shfl_xor(m0[rr], off));

    #pragma unroll
    for (int rr = 0; rr < 4; ++rr) {
        float s = 0.f;
        #pragma unroll
        for (int nf = 0; nf < 8; ++nf) s += __expf((accs[nf][rr] - m0[rr]) * inv_e);
        s0[rr] = s;
    }
    #pragma unroll
    for (int off = 1; off < 16; off <<= 1)
        #pragma unroll
        for (int rr = 0; rr < 4; ++rr) s0[rr] += __shfl_xor(s0[rr], off);

    // lanes with l15 = k (<12) and lk = k>>2 hold pos score in accs[8][k&3]
    if (l15 < K_ && lk == (l15 >> 2)) {
        int k = l15;
        #pragma unroll
        for (int rr = 0; rr < 4; ++rr) {
            if ((k & 3) == rr) {
                float ps   = accs[8][rr] * inv_e;
                float mneg = m0[rr] * inv_e;
                float M    = fmaxf(mneg, ps);
                float tot  = s0[rr] * __expf(mneg - M) + __expf(ps - M);
                partial[k * BW + p]        = M + __logf(tot) - ps;       // loss term
                partial[(12 + k) * BW + p] = (ps >= mneg) ? 1.0f : 0.0f; // argmax==0
            }
        }
    }
}

// ---- kernel 3: final mean over 3712 pairs, float32 outputs ----
__global__ void k_reduce(const float* __restrict__ partial, float* __restrict__ out) {
    int o = blockIdx.x;                  // 0..23
    float s = 0.f;
    for (int i = threadIdx.x; i < BW; i += 256) s += partial[o * BW + i];
    #pragma unroll
    for (int off = 32; off > 0; off >>= 1) s += __shfl_xor(s, off);
    __shared__ float w4[4];
    if ((threadIdx.x & 63) == 0) w4[threadIdx.x >> 6] = s;
    __syncthreads();
    if (threadIdx.x == 0)
        out[o] = (w4[0] + w4[1] + w4[2] + w4[3]) * (1.0f / BW);
}

extern "C" void kernel_launch(void* const* d_in, const int* in_sizes, int n_in,
                              void* d_out, int out_size, void* d_ws, size_t ws_size,
                              hipStream_t stream) {
    const float* cFeat = (const float*)d_in[0];
    const float* E     = (const float*)d_in[1];
    const float* Wp    = (const float*)d_in[2];
    const int*   idx   = (const int*)d_in[3];

    char* ws = (char*)d_ws;
    unsigned char*  locC8   = (unsigned char*) (ws);             // 11,403,264 B
    unsigned short* Abf     = (unsigned short*)(ws + 22806528);  //  2,097,152 B
    unsigned short* Wpbf    = (unsigned short*)(ws + 24903680);  //  1,572,864 B
    float*          partial = (float*)        (ws + 26476544);   //    356,352 B
    unsigned char*  Ebf8    = (unsigned char*) (ws + 26833024);  //  1,048,576 B
    unsigned short* idxT    = (unsigned short*)(ws + 27881600);  //    950,272 B

    k_prep<<<2816 + 32, 256, 0, stream>>>(cFeat, Wp, E, idx, Abf, Wpbf, Ebf8, idxT);
    k_locc<<<12 * 58, 256, 0, stream>>>(Abf, Wpbf, locC8);
    k_score<<<BW / 4, 256, 0, stream>>>(Ebf8, idxT, locC8, partial);
    k_reduce<<<24, 256, 0, stream>>>(partial, (float*)d_out);
}

// Round 10
// 111.882 us; speedup vs baseline: 1.0123x; 1.0123x over previous
//
#include <hip/hip_runtime.h>

#define HD __device__ __forceinline__

typedef __attribute__((ext_vector_type(4))) float f32x4;
typedef __attribute__((ext_vector_type(8))) short bf16x8;
typedef __attribute__((ext_vector_type(2))) long i64x2;

constexpr int B_ = 32, S_ = 128, DA = 256, DE = 256, K_ = 12, N_ = 128;
constexpr int W_ = S_ - K_;          // 116
constexpr int BW = B_ * W_;          // 3712

HD unsigned short f2bf(float f) {
    unsigned u = __float_as_uint(f);
    u += 0x7fffu + ((u >> 16) & 1u);          // round-to-nearest-even
    return (unsigned short)(u >> 16);
}

HD void gl2lds16(const void* g, void* l) {    // 16-byte global->LDS async copy
    __builtin_amdgcn_global_load_lds(
        (const __attribute__((address_space(1))) unsigned int*)g,
        (__attribute__((address_space(3))) unsigned int*)l, 16, 0, 0);
}

// ---- kernel 0: casts (A,Wp -> bf16; E -> fp8) + idxT u16 LDS-transpose + zero d_out ----
__global__ void k_prep(const float* __restrict__ A, const float* __restrict__ Wp,
                       const float* __restrict__ E, const int* __restrict__ idx,
                       unsigned short* __restrict__ Abf, unsigned short* __restrict__ Wpbf,
                       unsigned char* __restrict__ Ebf8, unsigned short* __restrict__ idxT,
                       float* __restrict__ dout) {
    int bx = blockIdx.x;
    if (bx < 1792) {                      // bf16 casts: A (1024 blocks), Wp (768)
        const float* src = (bx < 1024) ? A : Wp;
        unsigned short* dst = (bx < 1024) ? Abf : Wpbf;
        int base = (bx < 1024) ? bx : bx - 1024;
        int i = base * 256 + threadIdx.x;
        float4 v = ((const float4*)src)[i];
        ushort4 o;
        o.x = f2bf(v.x); o.y = f2bf(v.y); o.z = f2bf(v.z); o.w = f2bf(v.w);
        ((ushort4*)dst)[i] = o;
    } else if (bx < 2816) {               // E -> fp8 e4m3 (1024 blocks)
        int i = (bx - 1792) * 256 + threadIdx.x;
        float4 v = ((const float4*)E)[i];
        int w = __builtin_amdgcn_cvt_pk_fp8_f32(v.x, v.y, 0, false);
        w     = __builtin_amdgcn_cvt_pk_fp8_f32(v.z, v.w, w, true);
        ((unsigned int*)Ebf8)[i] = w;
    } else if (bx < 2848) {               // idxT: 32 blocks, one per b; both sides coalesced
        __shared__ unsigned short lt[W_][130];
        int b = bx - 2816;
        const int* ib = idx + b * N_ * W_;
        for (int i = threadIdx.x; i < N_ * W_; i += 256) {
            int n = i / W_, w = i - n * W_;
            lt[w][n] = (unsigned short)ib[i];
        }
        __syncthreads();
        unsigned short* ob = idxT + b * W_ * N_;
        for (int o = threadIdx.x; o < W_ * N_; o += 256) {
            int w = o >> 7, n = o & 127;
            ob[o] = lt[w][n];
        }
    } else {                              // zero the 24 output accumulators
        if (threadIdx.x < 24) dout[threadIdx.x] = 0.f;
    }
}

// ---- kernel 1: locC8[m][k][e] = fp8(sum_a A[m][a] * Wp[k][e][a]) ----
// m97-style: global_load_lds width-16 staging into linear [128][32] chunk buffers.
// Transposed epilogue: mfma(Wp_frag, A_frag) -> D row = e, col = m.
__global__ __launch_bounds__(256) void k_locc(const unsigned short* __restrict__ Abf,
                                              const unsigned short* __restrict__ Wpbf,
                                              unsigned char* __restrict__ locC8) {
    __shared__ unsigned short As[128 * 32];   // 8 KB, linear (gl_lds requirement)
    __shared__ unsigned short Bs[128 * 32];   // 8 KB

    int bx = blockIdx.x;
    int k  = bx / 58;
    int r  = bx % 58;
    int mt = r >> 1;
    int et = r & 1;

    int tid  = threadIdx.x;
    int lane = tid & 63;
    int wid  = tid >> 6;
    int wr   = wid >> 1, wc = wid & 1;   // wr: e-quadrant, wc: m-quadrant
    int l15  = lane & 15, lk = lane >> 4;

    // per-lane global sources for the 2 gl_lds issues per operand (rows j*16 + lane/4)
    int m0 = mt * 128 + wid * 32 + (lane >> 2);
    int m1 = m0 + 16;
    int b0 = m0 / W_, w0 = m0 - b0 * W_;
    int b1 = m1 / W_, w1 = m1 - b1 * W_;
    const unsigned short* aS0 = Abf + (size_t)(b0 * S_ + w0) * DA + (lane & 3) * 8;
    const unsigned short* aS1 = Abf + (size_t)(b1 * S_ + w1) * DA + (lane & 3) * 8;
    int e0 = et * 128 + wid * 32 + (lane >> 2);
    const unsigned short* bS0 = Wpbf + (size_t)(k * DE + e0) * DA + (lane & 3) * 8;
    const unsigned short* bS1 = bS0 + 16 * DA;
    unsigned short* aD0 = As + (wid * 32) * 32;        // wave-uniform LDS bases
    unsigned short* aD1 = As + (wid * 32 + 16) * 32;
    unsigned short* bD0 = Bs + (wid * 32) * 32;
    unsigned short* bD1 = Bs + (wid * 32 + 16) * 32;

    f32x4 acc[4][4] = {};

    for (int c = 0; c < 8; ++c) {
        __syncthreads();                 // prev chunk's ds_reads done before overwrite
        gl2lds16(aS0 + c * 32, aD0);
        gl2lds16(aS1 + c * 32, aD1);
        gl2lds16(bS0 + c * 32, bD0);
        gl2lds16(bS1 + c * 32, bD1);
        __syncthreads();                 // compiler drains vmcnt before barrier
        bf16x8 af[4], bfv[4];
        #pragma unroll
        for (int f = 0; f < 4; ++f) {
            af[f]  = *(const bf16x8*)&As[(wc * 64 + f * 16 + l15) * 32 + lk * 8];  // m rows
            bfv[f] = *(const bf16x8*)&Bs[(wr * 64 + f * 16 + l15) * 32 + lk * 8];  // e rows
        }
        #pragma unroll
        for (int fi = 0; fi < 4; ++fi)      // fi: e fragment (D row)
            #pragma unroll
            for (int fj = 0; fj < 4; ++fj)  // fj: m fragment (D col)
                acc[fi][fj] = __builtin_amdgcn_mfma_f32_16x16x32_bf16(bfv[fi], af[fj], acc[fi][fj], 0, 0, 0);
    }

    // D layout: col = lane&15 -> m, row = (lane>>4)*4 + rr -> e (4 consecutive e per lane)
    #pragma unroll
    for (int fi = 0; fi < 4; ++fi) {
        #pragma unroll
        for (int fj = 0; fj < 4; ++fj) {
            f32x4 v = acc[fi][fj];
            int mOut  = mt * 128 + wc * 64 + fj * 16 + l15;
            int eBase = et * 128 + wr * 64 + fi * 16 + lk * 4;
            int w = __builtin_amdgcn_cvt_pk_fp8_f32(v[0], v[1], 0, false);
            w     = __builtin_amdgcn_cvt_pk_fp8_f32(v[2], v[3], w, true);
            *(unsigned int*)(locC8 + (size_t)mOut * (K_ * DE) + k * DE + eBase) = w;
        }
    }
}

// ---- kernel 2: fp8 MFMA score + in-register LSE + fused block reduce -> d_out ----
__global__ __launch_bounds__(256, 2) void k_score(const unsigned char* __restrict__ Ebf8,
                                                  const unsigned short* __restrict__ idxT,
                                                  const unsigned char* __restrict__ locC8,
                                                  float* __restrict__ dout) {
    __shared__ float sacc[24];

    int tid  = threadIdx.x;
    int lane = tid & 63;
    int wid  = tid >> 6;
    int l15  = lane & 15, lk = lane >> 4;
    int p    = blockIdx.x * 4 + wid;     // pair index < 3712
    int b    = p / W_, w = p - b * W_;

    if (tid < 24) sacc[tid] = 0.f;
    __syncthreads();

    // gather rows for all 9 col-groups (u16 table, coalesced)
    int rows[9];
    #pragma unroll
    for (int nf = 0; nf < 8; ++nf)
        rows[nf] = idxT[p * N_ + nf * 16 + l15];
    rows[8] = b * S_ + ((l15 < K_) ? (w + l15 + 1) : 0);

    // A fragments: locC8[p][k=l15][e], rows k>=12 zeroed; 4 chunks of 64 e
    i64x2 af[4];
    const unsigned char* aBase = locC8 + (size_t)p * (K_ * DE) + l15 * DE + lk * 16;
    #pragma unroll
    for (int c = 0; c < 4; ++c) {
        i64x2 a = {};
        if (l15 < K_) a = *(const i64x2*)(aBase + c * 64);
        af[c] = a;
    }

    // hoist ALL B loads (36 x 16B) before any MFMA
    i64x2 bv[9][4];
    #pragma unroll
    for (int nf = 0; nf < 9; ++nf) {
        const unsigned char* bBase = Ebf8 + (size_t)rows[nf] * DE + lk * 16;
        #pragma unroll
        for (int c = 0; c < 4; ++c)
            bv[nf][c] = *(const i64x2*)(bBase + c * 64);
    }

    f32x4 accs[9];
    #pragma unroll
    for (int nf = 0; nf < 9; ++nf) {
        f32x4 acc = {};
        #pragma unroll
        for (int c = 0; c < 4; ++c) {
            acc = __builtin_amdgcn_mfma_f32_16x16x32_fp8_fp8(af[c][0], bv[nf][c][0], acc, 0, 0, 0);
            acc = __builtin_amdgcn_mfma_f32_16x16x32_fp8_fp8(af[c][1], bv[nf][c][1], acc, 0, 0, 0);
        }
        accs[nf] = acc;
    }

    constexpr float inv_e = 1.0f / 256.0f;
    constexpr float inv_bw = 1.0f / BW;

    // raw-max over the 8 neg groups (this lane's col slice), then 16-lane col-reduce
    float m0[4], s0[4];
    #pragma unroll
    for (int rr = 0; rr < 4; ++rr) {
        float mx = accs[0][rr];
        #pragma unroll
        for (int nf = 1; nf < 8; ++nf) mx = fmaxf(mx, accs[nf][rr]);
        m0[rr] = mx;
    }
    #pragma unroll
    for (int off = 1; off < 16; off <<= 1)
        #pragma unroll
        for (int rr = 0; rr < 4; ++rr) m0[rr] = fmaxf(m0[rr], __shfl_xor(m0[rr], off));

    #pragma unroll
    for (int rr = 0; rr < 4; ++rr) {
        float s = 0.f;
        #pragma unroll
        for (int nf = 0; nf < 8; ++nf) s += __expf((accs[nf][rr] - m0[rr]) * inv_e);
        s0[rr] = s;
    }
    #pragma unroll
    for (int off = 1; off < 16; off <<= 1)
        #pragma unroll
        for (int rr = 0; rr < 4; ++rr) s0[rr] += __shfl_xor(s0[rr], off);

    // lanes with l15 = k (<12) and lk = k>>2 hold pos score in accs[8][k&3]
    if (l15 < K_ && lk == (l15 >> 2)) {
        int k = l15;
        #pragma unroll
        for (int rr = 0; rr < 4; ++rr) {
            if ((k & 3) == rr) {
                float ps   = accs[8][rr] * inv_e;
                float mneg = m0[rr] * inv_e;
                float M    = fmaxf(mneg, ps);
                float tot  = s0[rr] * __expf(mneg - M) + __expf(ps - M);
                atomicAdd(&sacc[k],      (M + __logf(tot) - ps) * inv_bw);
                atomicAdd(&sacc[12 + k], (ps >= mneg) ? inv_bw : 0.0f);
            }
        }
    }
    __syncthreads();
    if (tid < 24) atomicAdd(&dout[tid], sacc[tid]);
}

extern "C" void kernel_launch(void* const* d_in, const int* in_sizes, int n_in,
                              void* d_out, int out_size, void* d_ws, size_t ws_size,
                              hipStream_t stream) {
    const float* cFeat = (const float*)d_in[0];
    const float* E     = (const float*)d_in[1];
    const float* Wp    = (const float*)d_in[2];
    const int*   idx   = (const int*)d_in[3];

    char* ws = (char*)d_ws;
    unsigned char*  locC8   = (unsigned char*) (ws);             // 11,403,264 B
    unsigned short* Abf     = (unsigned short*)(ws + 22806528);  //  2,097,152 B
    unsigned short* Wpbf    = (unsigned short*)(ws + 24903680);  //  1,572,864 B
    unsigned char*  Ebf8    = (unsigned char*) (ws + 26833024);  //  1,048,576 B
    unsigned short* idxT    = (unsigned short*)(ws + 27881600);  //    950,272 B
    float*          dout    = (float*)d_out;

    k_prep<<<2849, 256, 0, stream>>>(cFeat, Wp, E, idx, Abf, Wpbf, Ebf8, idxT, dout);
    k_locc<<<12 * 58, 256, 0, stream>>>(Abf, Wpbf, locC8);
    k_score<<<BW / 4, 256, 0, stream>>>(Ebf8, idxT, locC8, dout);
}